// Round 1
// baseline (819.682 us; speedup 1.0000x reference)
//
#include <hip/hip_runtime.h>

#define B_ 4
#define N_ 8192
#define C_ 16
#define JT 512   // h' rows staged per LDS tile

// ---------------- proj: h_out[n][c] = b[c] + sum_k h_in[n][k] * W[c][k] ----------------
__global__ __launch_bounds__(256) void proj_kernel(const float* __restrict__ hin,
                                                   const float* __restrict__ W,
                                                   const float* __restrict__ bias,
                                                   float* __restrict__ hout,
                                                   int total_nodes) {
    __shared__ float Ws[C_ * C_];
    __shared__ float bs[C_];
    int t = threadIdx.x;
    if (t < C_ * C_) Ws[t] = W[t];
    if (t < C_) bs[t] = bias[t];
    __syncthreads();
    int n = blockIdx.x * 256 + t;
    if (n >= total_nodes) return;
    const float4* hv = (const float4*)(hin + (size_t)n * C_);
    float4 q0 = hv[0], q1 = hv[1], q2 = hv[2], q3 = hv[3];
    float hr[16] = {q0.x, q0.y, q0.z, q0.w, q1.x, q1.y, q1.z, q1.w,
                    q2.x, q2.y, q2.z, q2.w, q3.x, q3.y, q3.z, q3.w};
    float o[16];
#pragma unroll
    for (int c = 0; c < 16; ++c) {
        float s = bs[c];
#pragma unroll
        for (int k = 0; k < 16; ++k) s += hr[k] * Ws[c * 16 + k];
        o[c] = s;
    }
    float4* ov = (float4*)(hout + (size_t)n * C_);
    ov[0] = make_float4(o[0], o[1], o[2], o[3]);
    ov[1] = make_float4(o[4], o[5], o[6], o[7]);
    ov[2] = make_float4(o[8], o[9], o[10], o[11]);
    ov[3] = make_float4(o[12], o[13], o[14], o[15]);
}

// ---------------- agg: out[b,i,:] = relu( (sum_j adj[b,i,j] * h[b,j,:]) / deg[b,i] ) ----
// deg fused: deg[b,i] = sum_j adj[b,i,j], computed in the same pass.
// Block = 256 threads = 4 waves; wave w owns rows i0 + 4w .. i0 + 4w + 3.
__global__ __launch_bounds__(256) void agg_kernel(const float* __restrict__ adj,
                                                  const float* __restrict__ hin,
                                                  float* __restrict__ hout) {
    __shared__ float4 hs[JT][5];  // [j][quad], quad 0..3 used, [4] pad -> 20-word row stride
    const int b = blockIdx.y;
    const int i0 = blockIdx.x * 16;
    const int t = threadIdx.x;
    const int wave = t >> 6;
    const int lane = t & 63;
    const int r0 = i0 + wave * 4;

    const float* adjb = adj + (size_t)b * N_ * N_;
    const float* hb = hin + (size_t)b * N_ * C_;

    const float* ar[4];
#pragma unroll
    for (int r = 0; r < 4; ++r) ar[r] = adjb + (size_t)(r0 + r) * N_;

    float acc[4][16];
#pragma unroll
    for (int r = 0; r < 4; ++r)
#pragma unroll
        for (int c = 0; c < 16; ++c) acc[r][c] = 0.f;
    float rs[4] = {0.f, 0.f, 0.f, 0.f};

    for (int jt = 0; jt < N_; jt += JT) {
        // stage h'[jt .. jt+JT) into LDS (2048 float4, 8 per thread, coalesced)
        const float4* src = (const float4*)(hb + (size_t)jt * C_);
#pragma unroll
        for (int k = 0; k < (JT * C_ / 4) / 256; ++k) {
            int g = t + k * 256;
            hs[g >> 2][g & 3] = src[g];
        }
        __syncthreads();

#pragma unroll 2
        for (int jj = lane; jj < JT; jj += 64) {
            float4 q0 = hs[jj][0], q1 = hs[jj][1], q2 = hs[jj][2], q3 = hs[jj][3];
            float hv[16] = {q0.x, q0.y, q0.z, q0.w, q1.x, q1.y, q1.z, q1.w,
                            q2.x, q2.y, q2.z, q2.w, q3.x, q3.y, q3.z, q3.w};
#pragma unroll
            for (int r = 0; r < 4; ++r) {
                float av = ar[r][jt + jj];
                rs[r] += av;
#pragma unroll
                for (int c = 0; c < 16; ++c) acc[r][c] += av * hv[c];
            }
        }
        __syncthreads();
    }

    // cross-lane butterfly reduction (per wave; wave owns its rows exclusively)
#pragma unroll
    for (int r = 0; r < 4; ++r) {
#pragma unroll
        for (int c = 0; c < 16; ++c) {
            float v = acc[r][c];
            for (int m = 32; m >= 1; m >>= 1) v += __shfl_xor(v, m, 64);
            acc[r][c] = v;
        }
        float d = rs[r];
        for (int m = 32; m >= 1; m >>= 1) d += __shfl_xor(d, m, 64);
        rs[r] = d;
    }

    if (lane == 0) {
#pragma unroll
        for (int r = 0; r < 4; ++r) {
            float inv = 1.0f / rs[r];
            float o[16];
#pragma unroll
            for (int c = 0; c < 16; ++c) {
                float v = acc[r][c] * inv;
                o[c] = v > 0.f ? v : 0.f;
            }
            float4* dst = (float4*)(hout + (size_t)b * N_ * C_ + (size_t)(r0 + r) * C_);
            dst[0] = make_float4(o[0], o[1], o[2], o[3]);
            dst[1] = make_float4(o[4], o[5], o[6], o[7]);
            dst[2] = make_float4(o[8], o[9], o[10], o[11]);
            dst[3] = make_float4(o[12], o[13], o[14], o[15]);
        }
    }
}

// ---------------- final: out[b,o] = b_fl[o] + sum_m h[b,m] * W_fl[o,m] ------------------
__global__ __launch_bounds__(256) void final_kernel(const float* __restrict__ h,
                                                    const float* __restrict__ Wfl,
                                                    const float* __restrict__ bfl,
                                                    float* __restrict__ out) {
    const int b = blockIdx.x >> 1;
    const int o = blockIdx.x & 1;
    const float4* hv = (const float4*)(h + (size_t)b * N_ * C_);
    const float4* wv = (const float4*)(Wfl + (size_t)o * N_ * C_);
    float s = 0.f;
    for (int m = threadIdx.x; m < (N_ * C_) / 4; m += 256) {
        float4 a = hv[m], w = wv[m];
        s += a.x * w.x + a.y * w.y + a.z * w.z + a.w * w.w;
    }
    for (int msk = 32; msk >= 1; msk >>= 1) s += __shfl_xor(s, msk, 64);
    __shared__ float wsum[4];
    int wave = threadIdx.x >> 6, lane = threadIdx.x & 63;
    if (lane == 0) wsum[wave] = s;
    __syncthreads();
    if (threadIdx.x == 0) {
        out[b * 2 + o] = wsum[0] + wsum[1] + wsum[2] + wsum[3] + bfl[o];
    }
}

extern "C" void kernel_launch(void* const* d_in, const int* in_sizes, int n_in,
                              void* d_out, int out_size, void* d_ws, size_t ws_size,
                              hipStream_t stream) {
    const float* x   = (const float*)d_in[0];  // node_features [B,N,16]
    const float* adj = (const float*)d_in[1];  // [B,N,N]
    const float* Wp  = (const float*)d_in[2];  // [16,16]
    const float* bp  = (const float*)d_in[3];  // [16]
    const float* Wfl = (const float*)d_in[4];  // [2, N*16]
    const float* bfl = (const float*)d_in[5];  // [2]
    float* out = (float*)d_out;

    float* hA = (float*)d_ws;                       // proj output   [B,N,16]
    float* hB = hA + (size_t)B_ * N_ * C_;          // agg output    [B,N,16]

    const int nodes = B_ * N_;
    dim3 aggGrid(N_ / 16, B_);

    // layer 1
    proj_kernel<<<(nodes + 255) / 256, 256, 0, stream>>>(x, Wp, bp, hA, nodes);
    agg_kernel<<<aggGrid, 256, 0, stream>>>(adj, hA, hB);
    // layer 2
    proj_kernel<<<(nodes + 255) / 256, 256, 0, stream>>>(hB, Wp, bp, hA, nodes);
    agg_kernel<<<aggGrid, 256, 0, stream>>>(adj, hA, hB);
    // layer 3
    proj_kernel<<<(nodes + 255) / 256, 256, 0, stream>>>(hB, Wp, bp, hA, nodes);
    agg_kernel<<<aggGrid, 256, 0, stream>>>(adj, hA, hB);

    final_kernel<<<B_ * 2, 256, 0, stream>>>(hB, Wfl, bfl, out);
}